// Round 17
// baseline (235.376 us; speedup 1.0000x reference)
//
#include <hip/hip_runtime.h>
#include <hip/hip_fp16.h>

using i32x4  = __attribute__((ext_vector_type(4)))  int;
using i32x16 = __attribute__((ext_vector_type(16))) int;

static constexpr int M  = 4 * 2048;   // 8192 rows (B*S)
static constexpr int N  = 4096;       // OUT_F
static constexpr int K  = 4096;       // IN_F
static constexpr int NT = K / 64;     // 64 K-tiles
static constexpr int TILE = 128 * 64; // 8192 B packed int8 panel-tile

// ---------------- fused pack kernel: int32 -> blocked int8 tiles -------------
// tile (8 KB): [kg(4)][row(128)][16B]  wa: [M/128][NT][tile], wb: [N/128][NT][tile]
static constexpr int PX_BLOCKS = (int)((size_t)M * K / 16 / 256);  // 8192
static constexpr int PW_BLOCKS = (int)((size_t)N * K / 16 / 256);  // 4096

__device__ __forceinline__ unsigned pack4(i32x4 v) {
  return (unsigned)((v.x & 255) | ((v.y & 255) << 8) | ((v.z & 255) << 16) | (v.w << 24));
}

__global__ __launch_bounds__(256) void pack_kernel(const int* __restrict__ x,
                                                   const int* __restrict__ w,
                                                   unsigned char* __restrict__ wa,
                                                   unsigned char* __restrict__ wb) {
  if (blockIdx.x < PX_BLOCKS) {
    unsigned g = blockIdx.x * 256 + threadIdx.x;     // dest 16B granule, < M*K/16
    unsigned tile = g >> 9, gt = g & 511;
    unsigned kg = gt >> 7, row = gt & 127;
    unsigned br = tile >> 6, kt = tile & 63;
    const int* src = x + ((size_t)(br * 128 + row) * K + kt * 64 + kg * 16);
    i32x4 v0 = *(const i32x4*)(src + 0);
    i32x4 v1 = *(const i32x4*)(src + 4);
    i32x4 v2 = *(const i32x4*)(src + 8);
    i32x4 v3 = *(const i32x4*)(src + 12);
    i32x4 d;
    d.x = (int)pack4(v0); d.y = (int)pack4(v1); d.z = (int)pack4(v2); d.w = (int)pack4(v3);
    *(i32x4*)(wa + (size_t)g * 16) = d;
  } else {
    unsigned g = (blockIdx.x - PX_BLOCKS) * 256 + threadIdx.x;  // < N*K/16
    unsigned tile = g >> 9, gt = g & 511;
    unsigned kg = gt >> 7, col = gt & 127;
    unsigned bn = tile >> 6, kt = tile & 63;
    unsigned n  = bn * 128 + col;
    unsigned k0 = kt * 64 + kg * 16;
    const int* src = w + (size_t)k0 * N + n;
    i32x4 d;
#pragma unroll
    for (int j = 0; j < 4; ++j) {
      int b0 = src[(size_t)(j * 4 + 0) * N];
      int b1 = src[(size_t)(j * 4 + 1) * N];
      int b2 = src[(size_t)(j * 4 + 2) * N];
      int b3 = src[(size_t)(j * 4 + 3) * N];
      d[j] = (b0 & 255) | ((b1 & 255) << 8) | ((b2 & 255) << 16) | (b3 << 24);
    }
    *(i32x4*)(wb + (size_t)g * 16) = d;
  }
}

// -- GEMM: NO LDS, NO BARRIERS, MAX TLP. Wave tile 64x64 (acc[2][2]=64 AGPR), -
//    single-stage reg buffer, ~110 unified regs -> 4 waves/SIMD (16 waves/CU).
//    Every wave an independent stream; latency hidden by sibling waves.

__global__ __launch_bounds__(256, 4) void gemm_i8(const unsigned char* __restrict__ wa,
                                                  const unsigned char* __restrict__ wb,
                                                  const __half* __restrict__ bias,
                                                  const float* __restrict__ alphaP,
                                                  float* __restrict__ out) {
  const int tid  = threadIdx.x;
  const int lane = tid & 63;
  const int w    = tid >> 6;            // wave 0..3
  const int wr   = w >> 1, wc = w & 1;  // 2 x 2 grid; wave tile 64 x 64
  const int l31  = lane & 31;
  const int kgl  = lane >> 5;

  const int bc = blockIdx.x;            // 0..31 (fast: neighbors share A panel)
  const int br = blockIdx.y;            // 0..63

  const unsigned char* gaw = wa + (size_t)br * NT * TILE;   // 128-row A panel
  const unsigned char* gbw = wb + (size_t)bc * NT * TILE;   // 128-col B panel

  // constant per-lane byte offsets within a tile (kc0; kc1 = +4096)
  const int aoff = kgl * 2048 + (wr * 64 + l31) * 16;
  const int boff = kgl * 2048 + (wc * 64 + l31) * 16;

  // single stage set: 8 x i32x4 = 32 VGPR
  i32x4 a0, a1, b0, b1, c0, c1, d0, d1;

#define LOADT(T) do {                                                \
    const unsigned char* at = gaw + (size_t)(T) * TILE;              \
    const unsigned char* bt = gbw + (size_t)(T) * TILE;              \
    a0 = *(const i32x4*)(at + aoff);                                 \
    a1 = *(const i32x4*)(at + aoff + 512);                           \
    b0 = *(const i32x4*)(bt + boff);                                 \
    b1 = *(const i32x4*)(bt + boff + 512);                           \
    c0 = *(const i32x4*)(at + 4096 + aoff);                          \
    c1 = *(const i32x4*)(at + 4096 + aoff + 512);                    \
    d0 = *(const i32x4*)(bt + 4096 + boff);                          \
    d1 = *(const i32x4*)(bt + 4096 + boff + 512);                    \
  } while (0)

  i32x16 acc[2][2] = {};

#define MF(mi, ni, A, B) \
  acc[mi][ni] = __builtin_amdgcn_mfma_i32_32x32x32_i8(A, B, acc[mi][ni], 0, 0, 0)

  LOADT(0);
  for (int t = 0; t < NT; ++t) {
    // kc0 then kc1; compiler inserts counted vmcnt per operand
    MF(0, 0, a0, b0); MF(0, 1, a0, b1);
    MF(1, 0, a1, b0); MF(1, 1, a1, b1);
    MF(0, 0, c0, d0); MF(0, 1, c0, d1);
    MF(1, 0, c1, d0); MF(1, 1, c1, d1);
    if (t + 1 < NT) LOADT(t + 1);   // safe WAR: MFMA reads operands at issue
  }

  // epilogue: C/D layout col=lane&31, row=(r&3)+8*(r>>2)+4*(lane>>5)
  const float alpha = *alphaP;
  const int row0 = br * 128 + wr * 64 + 4 * kgl;
  const int col0 = bc * 128 + wc * 64 + l31;
#pragma unroll
  for (int ni = 0; ni < 2; ++ni) {
    const int col = col0 + ni * 32;
    const float bf = __half2float(bias[col]);
#pragma unroll
    for (int mi = 0; mi < 2; ++mi) {
#pragma unroll
      for (int r = 0; r < 16; ++r) {
        const int row = row0 + mi * 32 + (r & 3) + 8 * (r >> 2);
        out[(size_t)row * N + col] = ((float)acc[mi][ni][r] + bf) * alpha;
      }
    }
  }
#undef MF
#undef LOADT
}

extern "C" void kernel_launch(void* const* d_in, const int* in_sizes, int n_in,
                              void* d_out, int out_size, void* d_ws, size_t ws_size,
                              hipStream_t stream) {
  const int*    x     = (const int*)d_in[0];
  const int*    wgt   = (const int*)d_in[1];
  const __half* bias  = (const __half*)d_in[2];
  const float*  alpha = (const float*)d_in[3];
  float*        out   = (float*)d_out;

  // workspace: packed A (32 MB) + packed B (16 MB) = 48 MB
  unsigned char* wa = (unsigned char*)d_ws;
  unsigned char* wb = wa + (size_t)M * K;

  pack_kernel<<<PX_BLOCKS + PW_BLOCKS, 256, 0, stream>>>(x, wgt, wa, wb);

  dim3 grid(N / 128, M / 128);   // 32 x 64 = 2048 blocks, 4 resident/CU
  gemm_i8<<<grid, 256, 0, stream>>>(wa, wb, bias, alpha, out);
}

// Round 18
// 227.253 us; speedup vs baseline: 1.0357x; 1.0357x over previous
//
#include <hip/hip_runtime.h>
#include <hip/hip_fp16.h>

using i32x4  = __attribute__((ext_vector_type(4)))  int;
using i32x16 = __attribute__((ext_vector_type(16))) int;

static constexpr int M  = 4 * 2048;   // 8192 rows (B*S)
static constexpr int N  = 4096;       // OUT_F
static constexpr int K  = 4096;       // IN_F
static constexpr int NT = K / 64;     // 64 K-tiles
static constexpr int NDT = K / 128;   // 32 double-tiles
static constexpr int ATILE = 256 * 64;  // 16 KB packed A tile (256-row)
static constexpr int BTILE = 128 * 64;  //  8 KB packed B tile (128-col)

// ---------------- fused pack kernel: int32 -> blocked int8 tiles -------------
// A tile (16 KB): [kg(4)][row(256)][16B]   wa: [M/256][NT][ATILE]
// B tile ( 8 KB): [kg(4)][col(128)][16B]   wb: [N/128][NT][BTILE] (transposed)
static constexpr int PX_BLOCKS = (int)((size_t)M * K / 16 / 256);  // 8192
static constexpr int PW_BLOCKS = (int)((size_t)N * K / 16 / 256);  // 4096

__device__ __forceinline__ unsigned pack4(i32x4 v) {
  return (unsigned)((v.x & 255) | ((v.y & 255) << 8) | ((v.z & 255) << 16) | (v.w << 24));
}

__global__ __launch_bounds__(256) void pack_kernel(const int* __restrict__ x,
                                                   const int* __restrict__ w,
                                                   unsigned char* __restrict__ wa,
                                                   unsigned char* __restrict__ wb) {
  if (blockIdx.x < PX_BLOCKS) {
    unsigned g = blockIdx.x * 256 + threadIdx.x;   // dest 16B granule, < M*K/16
    unsigned row = g & 255;
    unsigned kg  = (g >> 8) & 3;
    unsigned kt  = (g >> 10) & 63;
    unsigned br  = g >> 16;
    const int* src = x + ((size_t)(br * 256 + row) * K + kt * 64 + kg * 16);
    i32x4 v0 = *(const i32x4*)(src + 0);
    i32x4 v1 = *(const i32x4*)(src + 4);
    i32x4 v2 = *(const i32x4*)(src + 8);
    i32x4 v3 = *(const i32x4*)(src + 12);
    i32x4 d;
    d.x = (int)pack4(v0); d.y = (int)pack4(v1); d.z = (int)pack4(v2); d.w = (int)pack4(v3);
    *(i32x4*)(wa + (size_t)g * 16) = d;
  } else {
    unsigned g = (blockIdx.x - PX_BLOCKS) * 256 + threadIdx.x;  // < N*K/16
    unsigned col = g & 127;
    unsigned kg  = (g >> 7) & 3;
    unsigned kt  = (g >> 9) & 63;
    unsigned bn  = g >> 15;
    unsigned n   = bn * 128 + col;
    unsigned k0  = kt * 64 + kg * 16;
    const int* src = w + (size_t)k0 * N + n;
    i32x4 d;
#pragma unroll
    for (int j = 0; j < 4; ++j) {
      int b0 = src[(size_t)(j * 4 + 0) * N];
      int b1 = src[(size_t)(j * 4 + 1) * N];
      int b2 = src[(size_t)(j * 4 + 2) * N];
      int b3 = src[(size_t)(j * 4 + 3) * N];
      d[j] = (b0 & 255) | ((b1 & 255) << 8) | ((b2 & 255) << 16) | (b3 << 24);
    }
    *(i32x4*)(wb + (size_t)g * 16) = d;
  }
}

// -- GEMM: PRODUCER-CONSUMER WAVE SPECIALIZATION. 256x128 block, 512 threads. -
// Waves 0-3 (one per SIMD): consumers — ds_read A + MFMA only (acc[4][2]),
//   B fetched direct L2->VGPR one double-tile ahead (covered by compute).
// Waves 4-7: producers — global_load_lds A into 3-slot ring (depth 2),
//   counted vmcnt(8); they absorb ALL global latency, consumers never stall
//   on vmem. One s_barrier per double-K-tile (BK=128).

__device__ __forceinline__ void gload_lds16(const void* g, void* l) {
  __builtin_amdgcn_global_load_lds((const __attribute__((address_space(1))) unsigned int*)g,
                                   (__attribute__((address_space(3))) unsigned int*)l,
                                   16, 0, 0);
}

#define FENCE()   asm volatile("" ::: "memory")
#define BARRIER() do { FENCE(); __builtin_amdgcn_s_barrier(); FENCE(); } while (0)

__global__ __launch_bounds__(512, 2) void gemm_i8(const unsigned char* __restrict__ wa,
                                                  const unsigned char* __restrict__ wb,
                                                  const __half* __restrict__ bias,
                                                  const float* __restrict__ alphaP,
                                                  float* __restrict__ out) {
  __shared__ __align__(16) unsigned char As[3][32768];   // 96 KB: 3 slots x 2 A-tiles

  const int tid  = threadIdx.x;
  const int lane = tid & 63;
  const int w    = tid >> 6;            // wave 0..7
  const int cw   = w & 3;               // role-local id; w<4 consumer, w>=4 producer
  const int cr   = cw >> 1, cc = cw & 1;// consumer 2x2 grid, wave tile 128x64
  const int l31  = lane & 31;
  const int kgl  = lane >> 5;

  const int bc = blockIdx.x;            // 0..31 (N/128)
  const int br = blockIdx.y;            // 0..31 (M/256)

  const unsigned char* ga = wa + (size_t)br * NT * ATILE;   // 256-row A panel
  const unsigned char* gb = wb + (size_t)bc * NT * BTILE;   // 128-col B panel

  if (w >= 4) {
    // ------------------------- PRODUCER ------------------------------------
    const int poff = cw * 8192;         // this wave's 8 KB segment of 32 KB slot

#define STAGE(DTI) do {                                                        \
      const unsigned char* src = ga + (size_t)(DTI) * 32768 + poff + lane * 16; \
      unsigned char* dst = &As[(DTI) % 3][poff];                               \
      gload_lds16(src +    0, dst +    0);                                     \
      gload_lds16(src + 1024, dst + 1024);                                     \
      gload_lds16(src + 2048, dst + 2048);                                     \
      gload_lds16(src + 3072, dst + 3072);                                     \
      gload_lds16(src + 4096, dst + 4096);                                     \
      gload_lds16(src + 5120, dst + 5120);                                     \
      gload_lds16(src + 6144, dst + 6144);                                     \
      gload_lds16(src + 7168, dst + 7168);                                     \
    } while (0)

    STAGE(0);
    STAGE(1);
    asm volatile("s_waitcnt vmcnt(8)" ::: "memory");   // slot 0 complete
    BARRIER();
    for (int dt = 0; dt < NDT; ++dt) {
      if (dt + 2 < NDT) STAGE(dt + 2);                 // slot (dt+2)%3: free
      if (dt + 2 < NDT)      asm volatile("s_waitcnt vmcnt(8)" ::: "memory");
      else if (dt + 1 < NDT) asm volatile("s_waitcnt vmcnt(0)" ::: "memory");
      BARRIER();                                       // dt+1 now resident
    }
#undef STAGE
    return;   // producers skip epilogue
  }

  // --------------------------- CONSUMER ------------------------------------
  const int arow = cr * 128 + l31;      // A frag row base
  const int bcol = cc * 64 + l31;       // B frag col base

  i32x4 b[2][2][2][2];                  // [parity][sub][kc][ni] — const indices
  i32x16 acc[4][2] = {};

#define BLOADSUB(PAR, SUB, BASE) do {                                          \
    b[PAR][SUB][0][0] = *(const i32x4*)((BASE) + (kgl)     * 2048 + (bcol +  0) * 16); \
    b[PAR][SUB][0][1] = *(const i32x4*)((BASE) + (kgl)     * 2048 + (bcol + 32) * 16); \
    b[PAR][SUB][1][0] = *(const i32x4*)((BASE) + (2 + kgl) * 2048 + (bcol +  0) * 16); \
    b[PAR][SUB][1][1] = *(const i32x4*)((BASE) + (2 + kgl) * 2048 + (bcol + 32) * 16); \
  } while (0)

#define BLOAD(PAR, DT) do {                                                    \
    const unsigned char* bt = gb + (size_t)(DT) * 16384;                       \
    BLOADSUB(PAR, 0, bt);                                                      \
    BLOADSUB(PAR, 1, bt + 8192);                                               \
  } while (0)

#define CHUNK(SLOT, SUB, KC, PAR) do {                                         \
    const unsigned char* Ap = (SLOT) + (SUB) * 16384 + ((KC) * 2 + kgl) * 4096; \
    i32x4 a0 = *(const i32x4*)(Ap + (arow +  0) * 16);                         \
    i32x4 a1 = *(const i32x4*)(Ap + (arow + 32) * 16);                         \
    i32x4 a2 = *(const i32x4*)(Ap + (arow + 64) * 16);                         \
    i32x4 a3 = *(const i32x4*)(Ap + (arow + 96) * 16);                         \
    acc[0][0] = __builtin_amdgcn_mfma_i32_32x32x32_i8(a0, b[PAR][SUB][KC][0], acc[0][0], 0, 0, 0); \
    acc[0][1] = __builtin_amdgcn_mfma_i32_32x32x32_i8(a0, b[PAR][SUB][KC][1], acc[0][1], 0, 0, 0); \
    acc[1][0] = __builtin_amdgcn_mfma_i32_32x32x32_i8(a1, b[PAR][SUB][KC][0], acc[1][0], 0, 0, 0); \
    acc[1][1] = __builtin_amdgcn_mfma_i32_32x32x32_i8(a1, b[PAR][SUB][KC][1], acc[1][1], 0, 0, 0); \
    acc[2][0] = __builtin_amdgcn_mfma_i32_32x32x32_i8(a2, b[PAR][SUB][KC][0], acc[2][0], 0, 0, 0); \
    acc[2][1] = __builtin_amdgcn_mfma_i32_32x32x32_i8(a2, b[PAR][SUB][KC][1], acc[2][1], 0, 0, 0); \
    acc[3][0] = __builtin_amdgcn_mfma_i32_32x32x32_i8(a3, b[PAR][SUB][KC][0], acc[3][0], 0, 0, 0); \
    acc[3][1] = __builtin_amdgcn_mfma_i32_32x32x32_i8(a3, b[PAR][SUB][KC][1], acc[3][1], 0, 0, 0); \
  } while (0)

#define CSTEP(DT, PAR) do {                                                    \
    if ((DT) + 1 < NDT) BLOAD(PAR ^ 1, (DT) + 1);   /* next B, covered by MFMA */ \
    const unsigned char* slot = &As[(DT) % 3][0];                              \
    CHUNK(slot, 0, 0, PAR);                                                    \
    CHUNK(slot, 0, 1, PAR);                                                    \
    CHUNK(slot, 1, 0, PAR);                                                    \
    CHUNK(slot, 1, 1, PAR);                                                    \
    BARRIER();                                                                 \
  } while (0)

  BLOAD(0, 0);
  BARRIER();                            // matches producer prologue barrier
  for (int dt = 0; dt < NDT; dt += 2) { // NDT = 32, even
    CSTEP(dt, 0);
    CSTEP(dt + 1, 1);
  }

  // epilogue: C/D layout col=lane&31, row=(r&3)+8*(r>>2)+4*(lane>>5)
  const float alpha = *alphaP;
  const int row0 = br * 256 + cr * 128 + 4 * kgl;
  const int col0 = bc * 128 + cc * 64 + l31;
#pragma unroll
  for (int ni = 0; ni < 2; ++ni) {
    const int col = col0 + ni * 32;
    const float bf = __half2float(bias[col]);
#pragma unroll
    for (int mi = 0; mi < 4; ++mi) {
#pragma unroll
      for (int r = 0; r < 16; ++r) {
        const int row = row0 + mi * 32 + (r & 3) + 8 * (r >> 2);
        out[(size_t)row * N + col] = ((float)acc[mi][ni][r] + bf) * alpha;
      }
    }
  }
#undef CSTEP
#undef CHUNK
#undef BLOAD
#undef BLOADSUB
}

extern "C" void kernel_launch(void* const* d_in, const int* in_sizes, int n_in,
                              void* d_out, int out_size, void* d_ws, size_t ws_size,
                              hipStream_t stream) {
  const int*    x     = (const int*)d_in[0];
  const int*    wgt   = (const int*)d_in[1];
  const __half* bias  = (const __half*)d_in[2];
  const float*  alpha = (const float*)d_in[3];
  float*        out   = (float*)d_out;

  // workspace: packed A (32 MB) + packed B (16 MB) = 48 MB
  unsigned char* wa = (unsigned char*)d_ws;
  unsigned char* wb = wa + (size_t)M * K;

  pack_kernel<<<PX_BLOCKS + PW_BLOCKS, 256, 0, stream>>>(x, wgt, wa, wb);

  dim3 grid(N / 128, M / 256);   // 32 x 32 = 1024 blocks, 1 resident/CU
  gemm_i8<<<grid, 512, 0, stream>>>(wa, wb, bias, alpha, out);
}